// Round 10
// baseline (459.276 us; speedup 1.0000x reference)
//
#include <hip/hip_runtime.h>
#include <hip/hip_bf16.h>
#include <stdint.h>

// ---------------------------------------------------------------------------
// bf16 pack/unpack via pure bit ops (proven clean in rounds 7-8)
// ---------------------------------------------------------------------------
__device__ __forceinline__ float blo(uint32_t u) { return __uint_as_float(u << 16); }
__device__ __forceinline__ float bhi(uint32_t u) { return __uint_as_float(u & 0xFFFF0000u); }
__device__ __forceinline__ uint32_t bpack(float lo, float hi) {
    uint32_t ulo = __float_as_uint(lo), uhi = __float_as_uint(hi);
    return ((ulo + 0x8000u) >> 16) | ((uhi + 0x8000u) & 0xFFFF0000u);
}

// ---------------------------------------------------------------------------
// DPP helpers: reductions within each 16-lane row (VALU pipe, no LDS traffic)
// ---------------------------------------------------------------------------
template <int CTRL>
__device__ __forceinline__ float dppmov(float v) {
    return __int_as_float(__builtin_amdgcn_update_dpp(
        0, __float_as_int(v), CTRL, 0xF, 0xF, true));
}
__device__ __forceinline__ float grp_sum16(float v) {
    v += dppmov<0xB1>(v);   // quad_perm xor1
    v += dppmov<0x4E>(v);   // quad_perm xor2
    v += dppmov<0x124>(v);  // row_ror:4
    v += dppmov<0x128>(v);  // row_ror:8
    return v;
}
__device__ __forceinline__ float grp_max16(float v) {
    v = fmaxf(v, dppmov<0xB1>(v));
    v = fmaxf(v, dppmov<0x4E>(v));
    v = fmaxf(v, dppmov<0x124>(v));
    v = fmaxf(v, dppmov<0x128>(v));
    return v;
}

// ---------------------------------------------------------------------------
// Generic fp32 tiled GEMM (unchanged) — used for Q projection and output GEMM
// ---------------------------------------------------------------------------
#define TM 64
#define TN 64
#define TK 16

__global__ __launch_bounds__(256) void gemm_tiled(
    const float* __restrict__ A, int lda,
    const float* __restrict__ B, int ldb,
    float* __restrict__ C, int ldc,
    int M, int N, int kc, const float* __restrict__ bias)
{
    __shared__ float As[TK][TM + 4];
    __shared__ float Bs[TK][TN + 4];
    const int tid = threadIdx.x;
    const int bm = blockIdx.y * TM;
    const int bn = blockIdx.x * TN;
    const int k0 = blockIdx.z * kc;
    C += (size_t)blockIdx.z * M * N;

    const int tx = tid & 15;
    const int ty = tid >> 4;

    float acc[4][4];
#pragma unroll
    for (int i = 0; i < 4; ++i)
#pragma unroll
        for (int j = 0; j < 4; ++j)
            acc[i][j] = bias ? bias[bn + tx * 4 + j] : 0.0f;

    const int ar = tid >> 2;
    const int ac = (tid & 3) * 4;
    const int br = tid >> 4;
    const int bc = (tid & 15) * 4;

    for (int kt = k0; kt < k0 + kc; kt += TK) {
        float4 a = *(const float4*)&A[(size_t)(bm + ar) * lda + kt + ac];
        float4 b = *(const float4*)&B[(size_t)(kt + br) * ldb + bn + bc];
        As[ac + 0][ar] = a.x; As[ac + 1][ar] = a.y;
        As[ac + 2][ar] = a.z; As[ac + 3][ar] = a.w;
        *(float4*)&Bs[br][bc] = b;
        __syncthreads();
#pragma unroll
        for (int kk = 0; kk < TK; ++kk) {
            float4 a4 = *(const float4*)&As[kk][ty * 4];
            float4 b4 = *(const float4*)&Bs[kk][tx * 4];
            float av[4] = {a4.x, a4.y, a4.z, a4.w};
            float bv[4] = {b4.x, b4.y, b4.z, b4.w};
#pragma unroll
            for (int i = 0; i < 4; ++i)
#pragma unroll
                for (int j = 0; j < 4; ++j)
                    acc[i][j] = fmaf(av[i], bv[j], acc[i][j]);
        }
        __syncthreads();
    }
#pragma unroll
    for (int i = 0; i < 4; ++i) {
        float4 o = make_float4(acc[i][0], acc[i][1], acc[i][2], acc[i][3]);
        *(float4*)&C[(size_t)(bm + ty * 4 + i) * ldc + bn + tx * 4] = o;
    }
}

// ---------------------------------------------------------------------------
// Same GEMM but epilogue writes bf16-PACKED adjacent-col pairs scaled by
// `scale`. K uses scale = 1/sqrt(512) (alpha-1 applied to q in attn);
// V uses scale = 1. attn reads these straight from global (16 KB/token,
// L1/L2-resident) -> zero LDS, zero barriers in attn.
// ---------------------------------------------------------------------------
__global__ __launch_bounds__(256) void gemm_tiled_pack(
    const float* __restrict__ A, int lda,
    const float* __restrict__ B, int ldb,
    uint32_t* __restrict__ C, int N,
    int kc, const float* __restrict__ bias, float scale)
{
    __shared__ float As[TK][TM + 4];
    __shared__ float Bs[TK][TN + 4];
    const int tid = threadIdx.x;
    const int bm = blockIdx.y * TM;
    const int bn = blockIdx.x * TN;

    const int tx = tid & 15;
    const int ty = tid >> 4;

    float acc[4][4];
#pragma unroll
    for (int i = 0; i < 4; ++i)
#pragma unroll
        for (int j = 0; j < 4; ++j)
            acc[i][j] = bias ? bias[bn + tx * 4 + j] : 0.0f;

    const int ar = tid >> 2;
    const int ac = (tid & 3) * 4;
    const int br = tid >> 4;
    const int bc = (tid & 15) * 4;

    for (int kt = 0; kt < kc; kt += TK) {
        float4 a = *(const float4*)&A[(size_t)(bm + ar) * lda + kt + ac];
        float4 b = *(const float4*)&B[(size_t)(kt + br) * ldb + bn + bc];
        As[ac + 0][ar] = a.x; As[ac + 1][ar] = a.y;
        As[ac + 2][ar] = a.z; As[ac + 3][ar] = a.w;
        *(float4*)&Bs[br][bc] = b;
        __syncthreads();
#pragma unroll
        for (int kk = 0; kk < TK; ++kk) {
            float4 a4 = *(const float4*)&As[kk][ty * 4];
            float4 b4 = *(const float4*)&Bs[kk][tx * 4];
            float av[4] = {a4.x, a4.y, a4.z, a4.w};
            float bv[4] = {b4.x, b4.y, b4.z, b4.w};
#pragma unroll
            for (int i = 0; i < 4; ++i)
#pragma unroll
                for (int j = 0; j < 4; ++j)
                    acc[i][j] = fmaf(av[i], bv[j], acc[i][j]);
        }
        __syncthreads();
    }
    const int n2 = N >> 1;
#pragma unroll
    for (int i = 0; i < 4; ++i) {
        uint2 o = make_uint2(
            bpack(acc[i][0] * scale, acc[i][1] * scale),
            bpack(acc[i][2] * scale, acc[i][3] * scale));
        *(uint2*)&C[(size_t)(bm + ty * 4 + i) * n2 + ((bn + tx * 4) >> 1)] = o;
    }
}

// ---------------------------------------------------------------------------
// Fused quarter-token attn, round 9: register core IDENTICAL to round 8
// (single x[32], one row per 16-lane group, same pragmas, same mean-seeded
// exact active-set solver). Data source changed: K/V read bf16-packed
// DIRECTLY from global (no LDS, no __syncthreads) — occupancy becomes
// VGPR-limited (~8 waves/SIMD vs 3). q scaled by (alpha-1) at load (K
// carries the 1/sqrt(512)). Token mapping t = bid & 511 keeps a token's
// 4 quarter-blocks on one XCD (512 % 8 == 0) for L2 locality.
// ---------------------------------------------------------------------------
#define QROWS 128
#define NSOLVE 4
#define NBISECT 3
#define NNEWTON 6

__global__ __launch_bounds__(256, 4) void attn_entmax(
    const float* __restrict__ qg, const uint32_t* __restrict__ kp,
    const uint32_t* __restrict__ vp, float* resg,
    const float* __restrict__ alpha_p)
{
    const int t = blockIdx.x & 511;
    const int base = (blockIdx.x >> 9) * QROWS;
    const int tid = threadIdx.x;

    const float alpha = alpha_p[0];
    const float am1 = alpha - 1.0f;
    const float expo = 1.0f / am1;                 // = 2 for alpha=1.5 (exact)
    const bool fast = (expo == 2.0f);
    const float hispan = powf(1.0f / 512.0f, am1); // m - tau_hi

    const uint32_t* kt = kp + (size_t)t * 2048;
    const uint32_t* vt = vp + (size_t)t * 2048;
    const float*    qt = qg + (size_t)t * 4096;

    const int lane = tid & 63;
    const int w = tid >> 6;        // wave 0..3
    const int sub = lane >> 4;     // 16-lane group 0..3 (one row each)
    const int lx = lane & 15;

    for (int it = 0; it < QROWS / 16; ++it) {
        const int il = it * 16 + w * 4 + sub;   // local row 0..127

        float qv[8];
#pragma unroll
        for (int h = 0; h < 8; ++h) qv[h] = qt[h * 512 + base + il] * am1;

        // ---- scores; lane's 32 cols: j = 8*lx + 128*u + e  (e = 0..7)
        float x[32];
        float m = -1e30f, s1a = 0.0f;
#pragma unroll 2
        for (int u = 0; u < 4; ++u) {
            float a0=0,a1=0,a2=0,a3=0,a4=0,a5=0,a6=0,a7=0;
#pragma unroll
            for (int h = 0; h < 8; ++h) {
                uint4 kk = *(const uint4*)&kt[h * 256 + lx * 4 + 64 * u];
                float qh = qv[h];
                a0 = fmaf(qh, blo(kk.x), a0); a1 = fmaf(qh, bhi(kk.x), a1);
                a2 = fmaf(qh, blo(kk.y), a2); a3 = fmaf(qh, bhi(kk.y), a3);
                a4 = fmaf(qh, blo(kk.z), a4); a5 = fmaf(qh, bhi(kk.z), a5);
                a6 = fmaf(qh, blo(kk.w), a6); a7 = fmaf(qh, bhi(kk.w), a7);
            }
            x[8*u+0]=a0; x[8*u+1]=a1; x[8*u+2]=a2; x[8*u+3]=a3;
            x[8*u+4]=a4; x[8*u+5]=a5; x[8*u+6]=a6; x[8*u+7]=a7;
            m = fmaxf(m, fmaxf(fmaxf(fmaxf(a0,a1),fmaxf(a2,a3)),
                               fmaxf(fmaxf(a4,a5),fmaxf(a6,a7))));
            s1a += ((a0+a1)+(a2+a3)) + ((a4+a5)+(a6+a7));
        }
        m = grp_max16(m);
        const float tlo = m - 1.0f;            // f(tlo) >= 1 always
        const float thi = m - hispan;          // f(thi) <= 1 always

        float tau;
        if (fast) {
            s1a = grp_sum16(s1a);
            tau = fminf(fmaxf(s1a * (1.0f / 512.0f), tlo), thi);
#pragma unroll
            for (int itr = 0; itr < NSOLVE; ++itr) {
                float s1 = 0.0f, s2 = 0.0f, nf = 0.0f;
#pragma unroll
                for (int j = 0; j < 32; ++j) {
                    float r = x[j] - tau;
                    float rp = fmaxf(r, 0.0f);
                    s1 += rp;
                    s2 = fmaf(rp, rp, s2);
                    nf += (r > 0.0f) ? 1.0f : 0.0f;
                }
                s1 = grp_sum16(s1);
                s2 = grp_sum16(s2);
                nf = grp_sum16(nf);
                float disc = fmaxf(fmaf(s1, s1, -nf * (s2 - 1.0f)), 0.0f);
                tau += (s1 - sqrtf(disc)) / fmaxf(nf, 1.0f);
                tau = fminf(fmaxf(tau, tlo), thi);
            }
        } else {
            tau = tlo;
            float dm = 1.0f - hispan;
#pragma unroll
            for (int bi = 0; bi < NBISECT; ++bi) {
                dm *= 0.5f;
                float tm = tau + dm;
                float f = 0.0f;
#pragma unroll
                for (int j = 0; j < 32; ++j) {
                    float r = fmaxf(x[j] - tm, 0.0f);
                    f += __powf(r, expo);
                }
                f = grp_sum16(f);
                if (f >= 1.0f) tau = tm;
            }
#pragma unroll
            for (int ni = 0; ni < NNEWTON; ++ni) {
                float f = 0.0f, g = 0.0f;
#pragma unroll
                for (int j = 0; j < 32; ++j) {
                    float r = fmaxf(x[j] - tau, 0.0f);
                    float rp = __powf(r, expo - 1.0f);
                    g += rp; f += rp * r;
                }
                f = grp_sum16(f);
                g = grp_sum16(g);
                tau += (f - 1.0f) / fmaxf(expo * g, 1e-30f);
                tau = fminf(fmaxf(tau, tlo), thi);
            }
        }

        // ---- final (unnormalized) p into x; S for normalization
        float S = 0.0f;
        if (fast) {
#pragma unroll
            for (int j = 0; j < 32; ++j) {
                float r = fmaxf(x[j] - tau, 0.0f);
                x[j] = r * r; S += x[j];
            }
        } else {
#pragma unroll
            for (int j = 0; j < 32; ++j) {
                float r = fmaxf(x[j] - tau, 0.0f);
                x[j] = __powf(r, expo); S += x[j];
            }
        }
        S = grp_sum16(S);
        const float invS = 1.0f / S;

        // ---- res[h,i] = invS * sum_j p[j] * v[h,j]
#pragma unroll
        for (int h = 0; h < 8; ++h) {
            float a = 0.0f;
#pragma unroll 2
            for (int u = 0; u < 4; ++u) {
                uint4 vv = *(const uint4*)&vt[h * 256 + lx * 4 + 64 * u];
                a = fmaf(x[8*u+0], blo(vv.x), a);
                a = fmaf(x[8*u+1], bhi(vv.x), a);
                a = fmaf(x[8*u+2], blo(vv.y), a);
                a = fmaf(x[8*u+3], bhi(vv.y), a);
                a = fmaf(x[8*u+4], blo(vv.z), a);
                a = fmaf(x[8*u+5], bhi(vv.z), a);
                a = fmaf(x[8*u+6], blo(vv.w), a);
                a = fmaf(x[8*u+7], bhi(vv.w), a);
            }
            a = grp_sum16(a) * invS;
            if (lx == h) resg[(size_t)t * 4096 + h * 512 + base + il] = a;
        }
    }
}

// ---------------------------------------------------------------------------
__global__ __launch_bounds__(256) void reduce_bias(
    const float* __restrict__ part, const float* __restrict__ bu,
    float* __restrict__ out, int MN, int S)
{
    int i = blockIdx.x * 256 + threadIdx.x;
    if (i >= MN) return;
    float a = bu[i & 511];
#pragma unroll
    for (int s = 0; s < 8; ++s) a += part[(size_t)s * MN + i];
    out[i] = a;
}

// ---------------------------------------------------------------------------
extern "C" void kernel_launch(void* const* d_in, const int* in_sizes, int n_in,
                              void* d_out, int out_size, void* d_ws, size_t ws_size,
                              hipStream_t stream)
{
    const float* x  = (const float*)d_in[0];
    const float* Wq = (const float*)d_in[1];
    const float* bq = (const float*)d_in[2];
    const float* Wk = (const float*)d_in[3];
    const float* bk = (const float*)d_in[4];
    const float* Wv = (const float*)d_in[5];
    const float* bv = (const float*)d_in[6];
    const float* Wu = (const float*)d_in[7];
    const float* bu = (const float*)d_in[8];
    const float* al = (const float*)d_in[9];
    float* out = (float*)d_out;
    float* ws = (float*)d_ws;

    // ws layout (floats): q[2M] | kp-region[2M] | vp-region[2M]  (24 MB)
    // kp (packed K, 4 MB) lives in the k region; vp in the v region.
    // res aliases q (disjoint per-block row slices); split-K partials alias
    // the kp region (kp dead after attn_entmax; stream order guarantees it).
    float* q = ws;
    uint32_t* kpck = (uint32_t*)(ws + 2097152);
    uint32_t* vpck = (uint32_t*)(ws + 2 * 2097152);
    float* res = q;
    float* part = ws + 2097152;

    const float inv_sqrt_d = 0.04419417382415922f;  // 1/sqrt(512)
    dim3 blk(256);

    dim3 g1(4096 / TN, 512 / TM, 1);
    gemm_tiled<<<g1, blk, 0, stream>>>(x, 512, Wq, 4096, q, 4096, 512, 4096, 512, bq);
    gemm_tiled_pack<<<g1, blk, 0, stream>>>(x, 512, Wk, 4096, kpck, 4096, 512, bk, inv_sqrt_d);
    gemm_tiled_pack<<<g1, blk, 0, stream>>>(x, 512, Wv, 4096, vpck, 4096, 512, bv, 1.0f);

    // fused scores + alpha-entmax + P*V^T, quarter token per block, zero LDS
    attn_entmax<<<dim3(2048), blk, 0, stream>>>(q, kpck, vpck, res, al);

    dim3 g3(512 / TN, 512 / TM, 8);
    gemm_tiled<<<g3, blk, 0, stream>>>(res, 4096, Wu, 512, part, 512, 512, 512, 512, nullptr);
    reduce_bias<<<dim3(262144 / 256), blk, 0, stream>>>(part, bu, out, 262144, 8);
}

// Round 11
// 410.984 us; speedup vs baseline: 1.1175x; 1.1175x over previous
//
#include <hip/hip_runtime.h>
#include <hip/hip_bf16.h>
#include <stdint.h>

// ---------------------------------------------------------------------------
// bf16 pack/unpack via pure bit ops (proven clean in round 8)
// ---------------------------------------------------------------------------
__device__ __forceinline__ float blo(uint32_t u) { return __uint_as_float(u << 16); }
__device__ __forceinline__ float bhi(uint32_t u) { return __uint_as_float(u & 0xFFFF0000u); }
__device__ __forceinline__ uint32_t bpack(float lo, float hi) {
    uint32_t ulo = __float_as_uint(lo), uhi = __float_as_uint(hi);
    return ((ulo + 0x8000u) >> 16) | ((uhi + 0x8000u) & 0xFFFF0000u);
}

// ---------------------------------------------------------------------------
// DPP helpers: reductions within each 16-lane row (VALU pipe, no LDS traffic)
// ---------------------------------------------------------------------------
template <int CTRL>
__device__ __forceinline__ float dppmov(float v) {
    return __int_as_float(__builtin_amdgcn_update_dpp(
        0, __float_as_int(v), CTRL, 0xF, 0xF, true));
}
__device__ __forceinline__ float grp_sum16(float v) {
    v += dppmov<0xB1>(v);   // quad_perm xor1
    v += dppmov<0x4E>(v);   // quad_perm xor2
    v += dppmov<0x124>(v);  // row_ror:4
    v += dppmov<0x128>(v);  // row_ror:8
    return v;
}
__device__ __forceinline__ float grp_max16(float v) {
    v = fmaxf(v, dppmov<0xB1>(v));
    v = fmaxf(v, dppmov<0x4E>(v));
    v = fmaxf(v, dppmov<0x124>(v));
    v = fmaxf(v, dppmov<0x128>(v));
    return v;
}

// ---------------------------------------------------------------------------
// Generic fp32 tiled GEMM (unchanged)
// ---------------------------------------------------------------------------
#define TM 64
#define TN 64
#define TK 16

__global__ __launch_bounds__(256) void gemm_tiled(
    const float* __restrict__ A, int lda,
    const float* __restrict__ B, int ldb,
    float* __restrict__ C, int ldc,
    int M, int N, int kc, const float* __restrict__ bias)
{
    __shared__ float As[TK][TM + 4];
    __shared__ float Bs[TK][TN + 4];
    const int tid = threadIdx.x;
    const int bm = blockIdx.y * TM;
    const int bn = blockIdx.x * TN;
    const int k0 = blockIdx.z * kc;
    C += (size_t)blockIdx.z * M * N;

    const int tx = tid & 15;
    const int ty = tid >> 4;

    float acc[4][4];
#pragma unroll
    for (int i = 0; i < 4; ++i)
#pragma unroll
        for (int j = 0; j < 4; ++j)
            acc[i][j] = bias ? bias[bn + tx * 4 + j] : 0.0f;

    const int ar = tid >> 2;
    const int ac = (tid & 3) * 4;
    const int br = tid >> 4;
    const int bc = (tid & 15) * 4;

    for (int kt = k0; kt < k0 + kc; kt += TK) {
        float4 a = *(const float4*)&A[(size_t)(bm + ar) * lda + kt + ac];
        float4 b = *(const float4*)&B[(size_t)(kt + br) * ldb + bn + bc];
        As[ac + 0][ar] = a.x; As[ac + 1][ar] = a.y;
        As[ac + 2][ar] = a.z; As[ac + 3][ar] = a.w;
        *(float4*)&Bs[br][bc] = b;
        __syncthreads();
#pragma unroll
        for (int kk = 0; kk < TK; ++kk) {
            float4 a4 = *(const float4*)&As[kk][ty * 4];
            float4 b4 = *(const float4*)&Bs[kk][tx * 4];
            float av[4] = {a4.x, a4.y, a4.z, a4.w};
            float bv[4] = {b4.x, b4.y, b4.z, b4.w};
#pragma unroll
            for (int i = 0; i < 4; ++i)
#pragma unroll
                for (int j = 0; j < 4; ++j)
                    acc[i][j] = fmaf(av[i], bv[j], acc[i][j]);
        }
        __syncthreads();
    }
#pragma unroll
    for (int i = 0; i < 4; ++i) {
        float4 o = make_float4(acc[i][0], acc[i][1], acc[i][2], acc[i][3]);
        *(float4*)&C[(size_t)(bm + ty * 4 + i) * ldc + bn + tx * 4] = o;
    }
}

// ---------------------------------------------------------------------------
// Fused quarter-token attn, round 10 = round-8 kernel with ONE change:
// all 32-element in-lane reductions are explicitly TREE-structured
// (4 independent chains of 8 + 2-level combine) instead of 32-deep serial
// fp chains the compiler can't reassociate. Pure latency fix; data path,
// solver, pragmas, staging identical to round 8 (VGPR 60, zero scratch).
// ---------------------------------------------------------------------------
#define QROWS 128
#define NSOLVE 4
#define NBISECT 3
#define NNEWTON 6

__global__ __launch_bounds__(256, 4) void attn_entmax(
    const float* qg, const float* kg, const float* vg,
    float* resg, const float* __restrict__ alpha_p)
{
    __shared__ uint32_t ks16[8 * 256];   // [h][j2]: (k[h,2j2], k[h,2j2+1]) bf16
    __shared__ uint32_t vs16[8 * 256];   // [h][j2]: same packing for v
    __shared__ float    qs[8 * QROWS];   // pre-scaled f32 q, this block's rows

    const int t = blockIdx.x >> 2;
    const int base = (blockIdx.x & 3) * QROWS;
    const int tid = threadIdx.x;

    const float alpha = alpha_p[0];
    const float expo = 1.0f / (alpha - 1.0f);      // = 2 for alpha=1.5 (exact)
    const bool fast = (expo == 2.0f);
    const float scl = (alpha - 1.0f) * 0.04419417382415922f;  // (a-1)/sqrt(512)
    const float hispan = powf(1.0f / 512.0f, alpha - 1.0f);   // m - tau_hi

    {   // ---- stage K,V (bf16-packed) and q (f32, pre-scaled by scl)
        const float4* k4 = (const float4*)(kg + (size_t)t * 4096);
        const float4* v4 = (const float4*)(vg + (size_t)t * 4096);
#pragma unroll
        for (int a0 = 0; a0 < 4; ++a0) {
            int idx = tid + 256 * a0;          // h = idx>>7, j4 = idx&127
            int h = idx >> 7, j4 = idx & 127;
            float4 gk = k4[idx];
            float4 gv = v4[idx];
            *(uint2*)&ks16[h * 256 + 2 * j4] =
                make_uint2(bpack(gk.x, gk.y), bpack(gk.z, gk.w));
            *(uint2*)&vs16[h * 256 + 2 * j4] =
                make_uint2(bpack(gv.x, gv.y), bpack(gv.z, gv.w));
        }
        const float4* q4 = (const float4*)(qg + (size_t)t * 4096);
        {
            int h = tid >> 5, i4 = tid & 31;   // 256 float4 = 8h x 32
            float4 g = q4[h * 128 + (base >> 2) + i4];
            g.x *= scl; g.y *= scl; g.z *= scl; g.w *= scl;
            ((float4*)qs)[tid] = g;
        }
    }
    __syncthreads();

    const int lane = tid & 63;
    const int w = tid >> 6;        // wave 0..3
    const int sub = lane >> 4;     // 16-lane group 0..3 (one row each)
    const int lx = lane & 15;

    for (int it = 0; it < QROWS / 16; ++it) {
        const int il = it * 16 + w * 4 + sub;   // local row 0..127

        float qv[8];
#pragma unroll
        for (int h = 0; h < 8; ++h) qv[h] = qs[h * QROWS + il];

        // ---- scores; lane's 32 cols: j = 8*lx + 128*u + e  (e = 0..7)
        float x[32];
        float m = -1e30f, s1a = 0.0f;
#pragma unroll 2
        for (int u = 0; u < 4; ++u) {
            float a0=0,a1=0,a2=0,a3=0,a4=0,a5=0,a6=0,a7=0;
#pragma unroll
            for (int h = 0; h < 8; ++h) {
                uint4 kk = *(const uint4*)&ks16[h * 256 + lx * 4 + 64 * u];
                float qh = qv[h];
                a0 = fmaf(qh, blo(kk.x), a0); a1 = fmaf(qh, bhi(kk.x), a1);
                a2 = fmaf(qh, blo(kk.y), a2); a3 = fmaf(qh, bhi(kk.y), a3);
                a4 = fmaf(qh, blo(kk.z), a4); a5 = fmaf(qh, bhi(kk.z), a5);
                a6 = fmaf(qh, blo(kk.w), a6); a7 = fmaf(qh, bhi(kk.w), a7);
            }
            x[8*u+0]=a0; x[8*u+1]=a1; x[8*u+2]=a2; x[8*u+3]=a3;
            x[8*u+4]=a4; x[8*u+5]=a5; x[8*u+6]=a6; x[8*u+7]=a7;
            m = fmaxf(m, fmaxf(fmaxf(fmaxf(a0,a1),fmaxf(a2,a3)),
                               fmaxf(fmaxf(a4,a5),fmaxf(a6,a7))));
            s1a += ((a0+a1)+(a2+a3)) + ((a4+a5)+(a6+a7));
        }
        m = grp_max16(m);
        const float tlo = m - 1.0f;            // f(tlo) >= 1 always
        const float thi = m - hispan;          // f(thi) <= 1 always

        float tau;
        if (fast) {
            // seed: row mean, clamped into the bracket
            s1a = grp_sum16(s1a);
            tau = fminf(fmaxf(s1a * (1.0f / 512.0f), tlo), thi);
            // exact active-set solves; s1/s2/nf as 4 independent chains each
#pragma unroll
            for (int itr = 0; itr < NSOLVE; ++itr) {
                float p0=0,p1=0,p2=0,p3=0;
                float q0=0,q1=0,q2=0,q3=0;
                float c0=0,c1=0,c2=0,c3=0;
#pragma unroll
                for (int j = 0; j < 32; j += 4) {
                    float r0 = x[j+0] - tau, rp0 = fmaxf(r0, 0.0f);
                    float r1 = x[j+1] - tau, rp1 = fmaxf(r1, 0.0f);
                    float r2 = x[j+2] - tau, rp2 = fmaxf(r2, 0.0f);
                    float r3 = x[j+3] - tau, rp3 = fmaxf(r3, 0.0f);
                    p0 += rp0; p1 += rp1; p2 += rp2; p3 += rp3;
                    q0 = fmaf(rp0, rp0, q0); q1 = fmaf(rp1, rp1, q1);
                    q2 = fmaf(rp2, rp2, q2); q3 = fmaf(rp3, rp3, q3);
                    c0 += (r0 > 0.0f) ? 1.0f : 0.0f;
                    c1 += (r1 > 0.0f) ? 1.0f : 0.0f;
                    c2 += (r2 > 0.0f) ? 1.0f : 0.0f;
                    c3 += (r3 > 0.0f) ? 1.0f : 0.0f;
                }
                float s1 = (p0 + p1) + (p2 + p3);
                float s2 = (q0 + q1) + (q2 + q3);
                float nf = (c0 + c1) + (c2 + c3);
                s1 = grp_sum16(s1);
                s2 = grp_sum16(s2);
                nf = grp_sum16(nf);
                float disc = fmaxf(fmaf(s1, s1, -nf * (s2 - 1.0f)), 0.0f);
                tau += (s1 - sqrtf(disc)) / fmaxf(nf, 1.0f);
                tau = fminf(fmaxf(tau, tlo), thi);
            }
        } else {
            // generic alpha: bisect + Newton (powf path)
            tau = tlo;
            float dm = 1.0f - hispan;
#pragma unroll
            for (int bi = 0; bi < NBISECT; ++bi) {
                dm *= 0.5f;
                float tm = tau + dm;
                float f = 0.0f;
#pragma unroll
                for (int j = 0; j < 32; ++j) {
                    float r = fmaxf(x[j] - tm, 0.0f);
                    f += __powf(r, expo);
                }
                f = grp_sum16(f);
                if (f >= 1.0f) tau = tm;
            }
#pragma unroll
            for (int ni = 0; ni < NNEWTON; ++ni) {
                float f = 0.0f, g = 0.0f;
#pragma unroll
                for (int j = 0; j < 32; ++j) {
                    float r = fmaxf(x[j] - tau, 0.0f);
                    float rp = __powf(r, expo - 1.0f);
                    g += rp; f += rp * r;
                }
                f = grp_sum16(f);
                g = grp_sum16(g);
                tau += (f - 1.0f) / fmaxf(expo * g, 1e-30f);
                tau = fminf(fmaxf(tau, tlo), thi);
            }
        }

        // ---- final (unnormalized) p into x; S via 4 chains
        float S;
        if (fast) {
            float s0=0, s1c=0, s2c=0, s3c=0;
#pragma unroll
            for (int j = 0; j < 32; j += 4) {
                float r0 = fmaxf(x[j+0] - tau, 0.0f); x[j+0] = r0 * r0;
                float r1 = fmaxf(x[j+1] - tau, 0.0f); x[j+1] = r1 * r1;
                float r2 = fmaxf(x[j+2] - tau, 0.0f); x[j+2] = r2 * r2;
                float r3 = fmaxf(x[j+3] - tau, 0.0f); x[j+3] = r3 * r3;
                s0 += x[j+0]; s1c += x[j+1]; s2c += x[j+2]; s3c += x[j+3];
            }
            S = (s0 + s1c) + (s2c + s3c);
        } else {
            float s0=0, s1c=0, s2c=0, s3c=0;
#pragma unroll
            for (int j = 0; j < 32; j += 4) {
                float p0v = __powf(fmaxf(x[j+0] - tau, 0.0f), expo);
                float p1v = __powf(fmaxf(x[j+1] - tau, 0.0f), expo);
                float p2v = __powf(fmaxf(x[j+2] - tau, 0.0f), expo);
                float p3v = __powf(fmaxf(x[j+3] - tau, 0.0f), expo);
                x[j+0]=p0v; x[j+1]=p1v; x[j+2]=p2v; x[j+3]=p3v;
                s0 += p0v; s1c += p1v; s2c += p2v; s3c += p3v;
            }
            S = (s0 + s1c) + (s2c + s3c);
        }
        S = grp_sum16(S);
        const float invS = 1.0f / S;

        // ---- res[h,i] = invS * sum_j p[j] * v[h,j]; 4 fma chains per h
#pragma unroll
        for (int h = 0; h < 8; ++h) {
            float aA = 0.0f, aB = 0.0f, aC = 0.0f, aD = 0.0f;
#pragma unroll 2
            for (int u = 0; u < 4; ++u) {
                uint4 vv = *(const uint4*)&vs16[h * 256 + lx * 4 + 64 * u];
                aA = fmaf(x[8*u+0], blo(vv.x), aA);
                aB = fmaf(x[8*u+1], bhi(vv.x), aB);
                aC = fmaf(x[8*u+2], blo(vv.y), aC);
                aD = fmaf(x[8*u+3], bhi(vv.y), aD);
                aA = fmaf(x[8*u+4], blo(vv.z), aA);
                aB = fmaf(x[8*u+5], bhi(vv.z), aB);
                aC = fmaf(x[8*u+6], blo(vv.w), aC);
                aD = fmaf(x[8*u+7], bhi(vv.w), aD);
            }
            float a = ((aA + aB) + (aC + aD));
            a = grp_sum16(a) * invS;
            if (lx == h) resg[(size_t)t * 4096 + h * 512 + base + il] = a;
        }
    }
}

// ---------------------------------------------------------------------------
__global__ __launch_bounds__(256) void reduce_bias(
    const float* __restrict__ part, const float* __restrict__ bu,
    float* __restrict__ out, int MN, int S)
{
    int i = blockIdx.x * 256 + threadIdx.x;
    if (i >= MN) return;
    float a = bu[i & 511];
#pragma unroll
    for (int s = 0; s < 8; ++s) a += part[(size_t)s * MN + i];
    out[i] = a;
}

// ---------------------------------------------------------------------------
extern "C" void kernel_launch(void* const* d_in, const int* in_sizes, int n_in,
                              void* d_out, int out_size, void* d_ws, size_t ws_size,
                              hipStream_t stream)
{
    const float* x  = (const float*)d_in[0];
    const float* Wq = (const float*)d_in[1];
    const float* bq = (const float*)d_in[2];
    const float* Wk = (const float*)d_in[3];
    const float* bk = (const float*)d_in[4];
    const float* Wv = (const float*)d_in[5];
    const float* bv = (const float*)d_in[6];
    const float* Wu = (const float*)d_in[7];
    const float* bu = (const float*)d_in[8];
    const float* al = (const float*)d_in[9];
    float* out = (float*)d_out;
    float* ws = (float*)d_ws;

    // ws layout (floats): q[2M] | k[2M] | v[2M]
    // res aliases q (disjoint per-block row slices); split-K partials alias k.
    float* q = ws;
    float* k = ws + 2097152;
    float* v = ws + 2 * 2097152;
    float* res = q;
    float* part = k;

    dim3 blk(256);

    dim3 g1(4096 / TN, 512 / TM, 1);
    gemm_tiled<<<g1, blk, 0, stream>>>(x, 512, Wq, 4096, q, 4096, 512, 4096, 512, bq);
    gemm_tiled<<<g1, blk, 0, stream>>>(x, 512, Wk, 4096, k, 4096, 512, 4096, 512, bk);
    gemm_tiled<<<g1, blk, 0, stream>>>(x, 512, Wv, 4096, v, 4096, 512, 4096, 512, bv);

    // fused scores + alpha-entmax + P*V^T, quarter token per block
    attn_entmax<<<dim3(2048), blk, 0, stream>>>(q, k, v, res, al);

    dim3 g3(512 / TN, 512 / TM, 8);
    gemm_tiled<<<g3, blk, 0, stream>>>(res, 4096, Wu, 512, part, 512, 512, 512, 512, nullptr);
    reduce_bias<<<dim3(262144 / 256), blk, 0, stream>>>(part, bu, out, 262144, 8);
}

// Round 12
// 393.023 us; speedup vs baseline: 1.1686x; 1.0457x over previous
//
#include <hip/hip_runtime.h>
#include <hip/hip_bf16.h>
#include <stdint.h>

// ---------------------------------------------------------------------------
// Packed 2xfp32 helpers — lower to v_pk_fma_f32 / v_pk_add_f32 / v_pk_max_f32
// on gfx90a+ (CDNA2..4). Value-typed ext_vector only; array x2[] is indexed
// with the same static/unroll-2 discipline proven clean in rounds 2/6/10.
// ---------------------------------------------------------------------------
typedef float f32x2 __attribute__((ext_vector_type(2)));

__device__ __forceinline__ f32x2 mk2(float a, float b) { f32x2 r; r.x = a; r.y = b; return r; }
__device__ __forceinline__ f32x2 bc2(float a) { f32x2 r; r.x = a; r.y = a; return r; }
__device__ __forceinline__ f32x2 max2(f32x2 a, f32x2 b) {
#if __has_builtin(__builtin_elementwise_max)
    return __builtin_elementwise_max(a, b);
#else
    return mk2(fmaxf(a.x, b.x), fmaxf(a.y, b.y));
#endif
}
__device__ __forceinline__ f32x2 min2(f32x2 a, f32x2 b) {
#if __has_builtin(__builtin_elementwise_min)
    return __builtin_elementwise_min(a, b);
#else
    return mk2(fminf(a.x, b.x), fminf(a.y, b.y));
#endif
}

// ---------------------------------------------------------------------------
// DPP helpers: reductions within each 16-lane row (VALU pipe, no LDS traffic)
// ---------------------------------------------------------------------------
template <int CTRL>
__device__ __forceinline__ float dppmov(float v) {
    return __int_as_float(__builtin_amdgcn_update_dpp(
        0, __float_as_int(v), CTRL, 0xF, 0xF, true));
}
__device__ __forceinline__ float grp_sum16(float v) {
    v += dppmov<0xB1>(v);   // quad_perm xor1
    v += dppmov<0x4E>(v);   // quad_perm xor2
    v += dppmov<0x124>(v);  // row_ror:4
    v += dppmov<0x128>(v);  // row_ror:8
    return v;
}
__device__ __forceinline__ float grp_max16(float v) {
    v = fmaxf(v, dppmov<0xB1>(v));
    v = fmaxf(v, dppmov<0x4E>(v));
    v = fmaxf(v, dppmov<0x124>(v));
    v = fmaxf(v, dppmov<0x128>(v));
    return v;
}

// ---------------------------------------------------------------------------
// Generic fp32 tiled GEMM (unchanged)
// ---------------------------------------------------------------------------
#define TM 64
#define TN 64
#define TK 16

__global__ __launch_bounds__(256) void gemm_tiled(
    const float* __restrict__ A, int lda,
    const float* __restrict__ B, int ldb,
    float* __restrict__ C, int ldc,
    int M, int N, int kc, const float* __restrict__ bias)
{
    __shared__ float As[TK][TM + 4];
    __shared__ float Bs[TK][TN + 4];
    const int tid = threadIdx.x;
    const int bm = blockIdx.y * TM;
    const int bn = blockIdx.x * TN;
    const int k0 = blockIdx.z * kc;
    C += (size_t)blockIdx.z * M * N;

    const int tx = tid & 15;
    const int ty = tid >> 4;

    float acc[4][4];
#pragma unroll
    for (int i = 0; i < 4; ++i)
#pragma unroll
        for (int j = 0; j < 4; ++j)
            acc[i][j] = bias ? bias[bn + tx * 4 + j] : 0.0f;

    const int ar = tid >> 2;
    const int ac = (tid & 3) * 4;
    const int br = tid >> 4;
    const int bc = (tid & 15) * 4;

    for (int kt = k0; kt < k0 + kc; kt += TK) {
        float4 a = *(const float4*)&A[(size_t)(bm + ar) * lda + kt + ac];
        float4 b = *(const float4*)&B[(size_t)(kt + br) * ldb + bn + bc];
        As[ac + 0][ar] = a.x; As[ac + 1][ar] = a.y;
        As[ac + 2][ar] = a.z; As[ac + 3][ar] = a.w;
        *(float4*)&Bs[br][bc] = b;
        __syncthreads();
#pragma unroll
        for (int kk = 0; kk < TK; ++kk) {
            float4 a4 = *(const float4*)&As[kk][ty * 4];
            float4 b4 = *(const float4*)&Bs[kk][tx * 4];
            float av[4] = {a4.x, a4.y, a4.z, a4.w};
            float bv[4] = {b4.x, b4.y, b4.z, b4.w};
#pragma unroll
            for (int i = 0; i < 4; ++i)
#pragma unroll
                for (int j = 0; j < 4; ++j)
                    acc[i][j] = fmaf(av[i], bv[j], acc[i][j]);
        }
        __syncthreads();
    }
#pragma unroll
    for (int i = 0; i < 4; ++i) {
        float4 o = make_float4(acc[i][0], acc[i][1], acc[i][2], acc[i][3]);
        *(float4*)&C[(size_t)(bm + ty * 4 + i) * ldc + bn + tx * 4] = o;
    }
}

// ---------------------------------------------------------------------------
// Fused per-half-token attn, round 11 = round-6 structure (fp32 LDS, grid
// 1024, proven VGPR-clean) with the four hot elementwise loops converted to
// PACKED 2xfp32 (v_pk_*): fp32 float4 LDS reads feed pk_fma directly (no
// bf16 unpack), halving the instruction count of scores/PV and ~40% of the
// solver sweeps. Solver math identical (mean-seeded exact active-set).
// ---------------------------------------------------------------------------
#define NSOLVE 4
#define NBISECT 3
#define NNEWTON 6

__global__ __launch_bounds__(256, 4) void attn_entmax(
    const float* qg, const float* kg, const float* vg,
    float* resg, const float* __restrict__ alpha_p)
{
    __shared__ float ks[8 * 512];
    __shared__ float vs[8 * 512];
    __shared__ float qs[8 * 256];
    const int t = blockIdx.x >> 1;
    const int base = (blockIdx.x & 1) << 8;    // row half: 0 or 256
    const int tid = threadIdx.x;

    const float alpha = alpha_p[0];
    const float expo = 1.0f / (alpha - 1.0f);      // = 2 for alpha=1.5 (exact)
    const bool fast = (expo == 2.0f);
    const float scl = (alpha - 1.0f) * 0.04419417382415922f;  // (a-1)/sqrt(512)
    const float hispan = powf(1.0f / 512.0f, alpha - 1.0f);   // m - tau_hi

    {   // stage K, V (full token) and q (this block's 256 rows) — r6 verbatim
        const float4* k4 = (const float4*)(kg + (size_t)t * 4096);
        const float4* v4 = (const float4*)(vg + (size_t)t * 4096);
#pragma unroll
        for (int u = 0; u < 4; ++u) {
            int idx = tid + 256 * u;
            ((float4*)ks)[idx] = k4[idx];
            ((float4*)vs)[idx] = v4[idx];
        }
        const float4* q4 = (const float4*)(qg + (size_t)t * 4096);
#pragma unroll
        for (int u = 0; u < 2; ++u) {
            int idx = tid + 256 * u;               // = h*64 + j4
            ((float4*)qs)[idx] = q4[(idx >> 6) * 128 + (base >> 2) + (idx & 63)];
        }
    }
    __syncthreads();

    const int lane = tid & 63;
    const int w = tid >> 6;        // wave 0..3
    const int sub = lane >> 4;     // 16-lane group 0..3 (one row each)
    const int lx = lane & 15;

    const f32x2 zero2 = bc2(0.0f);
    const f32x2 one2  = bc2(1.0f);
    const f32x2 big2  = bc2(1e30f);
    const f32x2 scl2  = bc2(scl);

    for (int it = 0; it < 16; ++it) {
        const int il = it * 16 + w * 4 + sub;   // local row 0..255

        float qv[8];
#pragma unroll
        for (int h = 0; h < 8; ++h) qv[h] = qs[h * 256 + il];

        // ---- scores (packed): lane cols j = lx*4 + 64*u + {0..3}
        f32x2 x2[16];
        f32x2 mv = bc2(-1e30f), sv = zero2;
#pragma unroll 2
        for (int u = 0; u < 8; ++u) {
            f32x2 A = zero2, B = zero2;
#pragma unroll
            for (int h = 0; h < 8; ++h) {
                float4 k4 = *(const float4*)&ks[h * 512 + lx * 4 + 64 * u];
                f32x2 qh2 = bc2(qv[h]);
                A = qh2 * mk2(k4.x, k4.y) + A;   // v_pk_fma_f32
                B = qh2 * mk2(k4.z, k4.w) + B;
            }
            A = A * scl2;
            B = B * scl2;
            x2[2 * u] = A;
            x2[2 * u + 1] = B;
            mv = max2(mv, max2(A, B));
            sv = sv + A + B;
        }
        float m = grp_max16(fmaxf(mv.x, mv.y));
        const float tlo = m - 1.0f;            // f(tlo) >= 1 always
        const float thi = m - hispan;          // f(thi) <= 1 always

        float tau;
        if (fast) {
            // seed: row mean, clamped into the bracket
            float s1a = grp_sum16(sv.x + sv.y);
            tau = fminf(fmaxf(s1a * (1.0f / 512.0f), tlo), thi);
            // exact active-set solves, packed sweeps (2 chains of pairs)
#pragma unroll
            for (int itr = 0; itr < NSOLVE; ++itr) {
                f32x2 tau2 = bc2(tau);
                f32x2 s1A = zero2, s1B = zero2;
                f32x2 s2A = zero2, s2B = zero2;
                f32x2 cA = zero2, cB = zero2;
#pragma unroll
                for (int j = 0; j < 16; j += 2) {
                    f32x2 rA = x2[j] - tau2;
                    f32x2 rB = x2[j + 1] - tau2;
                    f32x2 rpA = max2(rA, zero2);
                    f32x2 rpB = max2(rB, zero2);
                    s1A = s1A + rpA;
                    s1B = s1B + rpB;
                    s2A = rpA * rpA + s2A;
                    s2B = rpB * rpB + s2B;
                    cA = cA + min2(rpA * big2, one2);   // step(rp): exact for any active gap
                    cB = cB + min2(rpB * big2, one2);
                }
                f32x2 s1v = s1A + s1B, s2v = s2A + s2B, cv = cA + cB;
                float s1 = grp_sum16(s1v.x + s1v.y);
                float s2 = grp_sum16(s2v.x + s2v.y);
                float nf = grp_sum16(cv.x + cv.y);
                float disc = fmaxf(fmaf(s1, s1, -nf * (s2 - 1.0f)), 0.0f);
                tau += (s1 - sqrtf(disc)) / fmaxf(nf, 1.0f);
                tau = fminf(fmaxf(tau, tlo), thi);
            }
        } else {
            // generic alpha: bisect + Newton (powf path, scalar components)
            tau = tlo;
            float dm = 1.0f - hispan;
#pragma unroll
            for (int bi = 0; bi < NBISECT; ++bi) {
                dm *= 0.5f;
                float tm = tau + dm;
                float f = 0.0f;
#pragma unroll
                for (int j = 0; j < 16; ++j) {
                    f += __powf(fmaxf(x2[j].x - tm, 0.0f), expo);
                    f += __powf(fmaxf(x2[j].y - tm, 0.0f), expo);
                }
                f = grp_sum16(f);
                if (f >= 1.0f) tau = tm;
            }
#pragma unroll
            for (int ni = 0; ni < NNEWTON; ++ni) {
                float f = 0.0f, g = 0.0f;
#pragma unroll
                for (int j = 0; j < 16; ++j) {
                    float r0 = fmaxf(x2[j].x - tau, 0.0f);
                    float rp0 = __powf(r0, expo - 1.0f);
                    g += rp0; f += rp0 * r0;
                    float r1 = fmaxf(x2[j].y - tau, 0.0f);
                    float rp1 = __powf(r1, expo - 1.0f);
                    g += rp1; f += rp1 * r1;
                }
                f = grp_sum16(f);
                g = grp_sum16(g);
                tau += (f - 1.0f) / fmaxf(expo * g, 1e-30f);
                tau = fminf(fmaxf(tau, tlo), thi);
            }
        }

        // ---- final (unnormalized) p into x2; S packed
        float S;
        if (fast) {
            f32x2 tau2 = bc2(tau);
            f32x2 SA = zero2, SB = zero2;
#pragma unroll
            for (int j = 0; j < 16; j += 2) {
                f32x2 rA = max2(x2[j] - tau2, zero2);
                f32x2 rB = max2(x2[j + 1] - tau2, zero2);
                f32x2 pA = rA * rA;
                f32x2 pB = rB * rB;
                x2[j] = pA;
                x2[j + 1] = pB;
                SA = SA + pA;
                SB = SB + pB;
            }
            f32x2 Sv = SA + SB;
            S = Sv.x + Sv.y;
        } else {
            float s0 = 0.0f;
#pragma unroll
            for (int j = 0; j < 16; ++j) {
                float p0 = __powf(fmaxf(x2[j].x - tau, 0.0f), expo);
                float p1 = __powf(fmaxf(x2[j].y - tau, 0.0f), expo);
                x2[j].x = p0; x2[j].y = p1;
                s0 += p0 + p1;
            }
            S = s0;
        }
        S = grp_sum16(S);
        const float invS = 1.0f / S;

        // ---- res[h,i] = invS * sum_j p[j] * v[h,j]  (packed fma, then hsum)
#pragma unroll
        for (int h = 0; h < 8; ++h) {
            f32x2 accA = zero2, accB = zero2;
#pragma unroll 2
            for (int u = 0; u < 8; ++u) {
                float4 v4 = *(const float4*)&vs[h * 512 + lx * 4 + 64 * u];
                accA = x2[2 * u] * mk2(v4.x, v4.y) + accA;
                accB = x2[2 * u + 1] * mk2(v4.z, v4.w) + accB;
            }
            float a = (accA.x + accA.y) + (accB.x + accB.y);
            a = grp_sum16(a) * invS;
            if (lx == h) resg[(size_t)t * 4096 + h * 512 + base + il] = a;
        }
    }
}

// ---------------------------------------------------------------------------
__global__ __launch_bounds__(256) void reduce_bias(
    const float* __restrict__ part, const float* __restrict__ bu,
    float* __restrict__ out, int MN, int S)
{
    int i = blockIdx.x * 256 + threadIdx.x;
    if (i >= MN) return;
    float a = bu[i & 511];
#pragma unroll
    for (int s = 0; s < 8; ++s) a += part[(size_t)s * MN + i];
    out[i] = a;
}

// ---------------------------------------------------------------------------
extern "C" void kernel_launch(void* const* d_in, const int* in_sizes, int n_in,
                              void* d_out, int out_size, void* d_ws, size_t ws_size,
                              hipStream_t stream)
{
    const float* x  = (const float*)d_in[0];
    const float* Wq = (const float*)d_in[1];
    const float* bq = (const float*)d_in[2];
    const float* Wk = (const float*)d_in[3];
    const float* bk = (const float*)d_in[4];
    const float* Wv = (const float*)d_in[5];
    const float* bv = (const float*)d_in[6];
    const float* Wu = (const float*)d_in[7];
    const float* bu = (const float*)d_in[8];
    const float* al = (const float*)d_in[9];
    float* out = (float*)d_out;
    float* ws = (float*)d_ws;

    // ws layout (floats): q[2M] | k[2M] | v[2M]
    // res aliases q (disjoint per-block row slices); split-K partials alias k.
    float* q = ws;
    float* k = ws + 2097152;
    float* v = ws + 2 * 2097152;
    float* res = q;
    float* part = k;

    dim3 blk(256);

    dim3 g1(4096 / TN, 512 / TM, 1);
    gemm_tiled<<<g1, blk, 0, stream>>>(x, 512, Wq, 4096, q, 4096, 512, 4096, 512, bq);
    gemm_tiled<<<g1, blk, 0, stream>>>(x, 512, Wk, 4096, k, 4096, 512, 4096, 512, bk);
    gemm_tiled<<<g1, blk, 0, stream>>>(x, 512, Wv, 4096, v, 4096, 512, 4096, 512, bv);

    // fused scores + alpha-entmax + P*V^T, half token per block
    attn_entmax<<<dim3(1024), blk, 0, stream>>>(q, k, v, res, al);

    dim3 g3(512 / TN, 512 / TM, 8);
    gemm_tiled<<<g3, blk, 0, stream>>>(res, 4096, Wu, 512, part, 512, 512, 512, 512, nullptr);
    reduce_bias<<<dim3(262144 / 256), blk, 0, stream>>>(part, bu, out, 262144, 8);
}

// Round 13
// 367.511 us; speedup vs baseline: 1.2497x; 1.0694x over previous
//
#include <hip/hip_runtime.h>
#include <hip/hip_bf16.h>
#include <stdint.h>

// ---------------------------------------------------------------------------
// Packed 2xfp32 helpers — lower to v_pk_fma_f32 / v_pk_add_f32 / v_pk_max_f32
// ---------------------------------------------------------------------------
typedef float f32x2 __attribute__((ext_vector_type(2)));

__device__ __forceinline__ f32x2 mk2(float a, float b) { f32x2 r; r.x = a; r.y = b; return r; }
__device__ __forceinline__ f32x2 bc2(float a) { f32x2 r; r.x = a; r.y = a; return r; }
__device__ __forceinline__ f32x2 max2(f32x2 a, f32x2 b) {
#if __has_builtin(__builtin_elementwise_max)
    return __builtin_elementwise_max(a, b);
#else
    return mk2(fmaxf(a.x, b.x), fmaxf(a.y, b.y));
#endif
}
__device__ __forceinline__ f32x2 min2(f32x2 a, f32x2 b) {
#if __has_builtin(__builtin_elementwise_min)
    return __builtin_elementwise_min(a, b);
#else
    return mk2(fminf(a.x, b.x), fminf(a.y, b.y));
#endif
}

// ---------------------------------------------------------------------------
// DPP helpers: reductions within each 16-lane row (VALU pipe, no LDS traffic)
// ---------------------------------------------------------------------------
template <int CTRL>
__device__ __forceinline__ float dppmov(float v) {
    return __int_as_float(__builtin_amdgcn_update_dpp(
        0, __float_as_int(v), CTRL, 0xF, 0xF, true));
}
__device__ __forceinline__ float grp_sum16(float v) {
    v += dppmov<0xB1>(v);   // quad_perm xor1
    v += dppmov<0x4E>(v);   // quad_perm xor2
    v += dppmov<0x124>(v);  // row_ror:4
    v += dppmov<0x128>(v);  // row_ror:8
    return v;
}
__device__ __forceinline__ float grp_max16(float v) {
    v = fmaxf(v, dppmov<0xB1>(v));
    v = fmaxf(v, dppmov<0x4E>(v));
    v = fmaxf(v, dppmov<0x124>(v));
    v = fmaxf(v, dppmov<0x128>(v));
    return v;
}

// ---------------------------------------------------------------------------
// fp32 tiled GEMM, inner loop PACKED (8 pk_fma vs 16 fma per k-step)
// ---------------------------------------------------------------------------
#define TM 64
#define TN 64
#define TK 16

__global__ __launch_bounds__(256) void gemm_tiled(
    const float* __restrict__ A, int lda,
    const float* __restrict__ B, int ldb,
    float* __restrict__ C, int ldc,
    int M, int N, int kc, const float* __restrict__ bias)
{
    __shared__ float As[TK][TM + 4];
    __shared__ float Bs[TK][TN + 4];
    const int tid = threadIdx.x;
    const int bm = blockIdx.y * TM;
    const int bn = blockIdx.x * TN;
    const int k0 = blockIdx.z * kc;
    C += (size_t)blockIdx.z * M * N;

    const int tx = tid & 15;
    const int ty = tid >> 4;

    f32x2 acc[4][2];
#pragma unroll
    for (int i = 0; i < 4; ++i) {
        if (bias) {
            acc[i][0] = mk2(bias[bn + tx * 4 + 0], bias[bn + tx * 4 + 1]);
            acc[i][1] = mk2(bias[bn + tx * 4 + 2], bias[bn + tx * 4 + 3]);
        } else {
            acc[i][0] = bc2(0.0f);
            acc[i][1] = bc2(0.0f);
        }
    }

    const int ar = tid >> 2;
    const int ac = (tid & 3) * 4;
    const int br = tid >> 4;
    const int bc = (tid & 15) * 4;

    for (int kt = k0; kt < k0 + kc; kt += TK) {
        float4 a = *(const float4*)&A[(size_t)(bm + ar) * lda + kt + ac];
        float4 b = *(const float4*)&B[(size_t)(kt + br) * ldb + bn + bc];
        As[ac + 0][ar] = a.x; As[ac + 1][ar] = a.y;
        As[ac + 2][ar] = a.z; As[ac + 3][ar] = a.w;
        *(float4*)&Bs[br][bc] = b;
        __syncthreads();
#pragma unroll
        for (int kk = 0; kk < TK; ++kk) {
            float4 a4 = *(const float4*)&As[kk][ty * 4];
            float4 b4 = *(const float4*)&Bs[kk][tx * 4];
            f32x2 b01 = mk2(b4.x, b4.y), b23 = mk2(b4.z, b4.w);
            float av[4] = {a4.x, a4.y, a4.z, a4.w};
#pragma unroll
            for (int i = 0; i < 4; ++i) {
                f32x2 ai = bc2(av[i]);
                acc[i][0] = ai * b01 + acc[i][0];   // v_pk_fma_f32
                acc[i][1] = ai * b23 + acc[i][1];
            }
        }
        __syncthreads();
    }
#pragma unroll
    for (int i = 0; i < 4; ++i) {
        float4 o = make_float4(acc[i][0].x, acc[i][0].y, acc[i][1].x, acc[i][1].y);
        *(float4*)&C[(size_t)(bm + ty * 4 + i) * ldc + bn + tx * 4] = o;
    }
}

// ---------------------------------------------------------------------------
// Fused per-half-token attn, round 12 = round-11 packed kernel + 2 ROWS PER
// 16-LANE GROUP (8 outer iters of 8 rows/wave): every K/V ds_read_b128 now
// feeds both rows' pk_fmas -> LDS instructions per row halve (the r11
// bottleneck); two independent solve chains add ILP. State: xa[16]+xb[16]
// f32x2 (=64 VGPR) under the never-scratched (256,3) bound; r2/r6/r11's
// unroll-2/static-pair indexing discipline kept verbatim.
// WRITE_SIZE == 8192 is the no-scratch tripwire.
// ---------------------------------------------------------------------------
#define NSOLVE 4
#define NBISECT 3
#define NNEWTON 6

__global__ __launch_bounds__(256, 3) void attn_entmax(
    const float* qg, const float* kg, const float* vg,
    float* resg, const float* __restrict__ alpha_p)
{
    __shared__ float ks[8 * 512];
    __shared__ float vs[8 * 512];
    __shared__ float qs[8 * 256];
    const int t = blockIdx.x >> 1;
    const int base = (blockIdx.x & 1) << 8;    // row half: 0 or 256
    const int tid = threadIdx.x;

    const float alpha = alpha_p[0];
    const float expo = 1.0f / (alpha - 1.0f);      // = 2 for alpha=1.5 (exact)
    const bool fast = (expo == 2.0f);
    const float scl = (alpha - 1.0f) * 0.04419417382415922f;  // (a-1)/sqrt(512)
    const float hispan = powf(1.0f / 512.0f, alpha - 1.0f);   // m - tau_hi

    {   // stage K, V (full token) and q (this block's 256 rows)
        const float4* k4 = (const float4*)(kg + (size_t)t * 4096);
        const float4* v4 = (const float4*)(vg + (size_t)t * 4096);
#pragma unroll
        for (int u = 0; u < 4; ++u) {
            int idx = tid + 256 * u;
            ((float4*)ks)[idx] = k4[idx];
            ((float4*)vs)[idx] = v4[idx];
        }
        const float4* q4 = (const float4*)(qg + (size_t)t * 4096);
#pragma unroll
        for (int u = 0; u < 2; ++u) {
            int idx = tid + 256 * u;               // = h*64 + j4
            ((float4*)qs)[idx] = q4[(idx >> 6) * 128 + (base >> 2) + (idx & 63)];
        }
    }
    __syncthreads();

    const int lane = tid & 63;
    const int w = tid >> 6;        // wave 0..3
    const int sub = lane >> 4;     // 16-lane group 0..3
    const int lx = lane & 15;

    const f32x2 zero2 = bc2(0.0f);
    const f32x2 one2  = bc2(1.0f);
    const f32x2 big2  = bc2(1e30f);
    const f32x2 scl2  = bc2(scl);

    for (int it = 0; it < 8; ++it) {
        const int il0 = it * 32 + w * 4 + sub;   // this group's row pair
        const int il1 = il0 + 16;

        float qv0[8], qv1[8];
#pragma unroll
        for (int h = 0; h < 8; ++h) {
            qv0[h] = qs[h * 256 + il0];
            qv1[h] = qs[h * 256 + il1];
        }

        // ---- scores for BOTH rows; lane cols j = lx*4 + 64*u + {0..3}
        f32x2 xa[16], xb[16];
        f32x2 mva = bc2(-1e30f), sva = zero2;
        f32x2 mvb = bc2(-1e30f), svb = zero2;
#pragma unroll 2
        for (int u = 0; u < 8; ++u) {
            f32x2 A0 = zero2, B0 = zero2, A1 = zero2, B1 = zero2;
#pragma unroll
            for (int h = 0; h < 8; ++h) {
                float4 k4 = *(const float4*)&ks[h * 512 + lx * 4 + 64 * u];
                f32x2 k01 = mk2(k4.x, k4.y), k23 = mk2(k4.z, k4.w);
                f32x2 q0 = bc2(qv0[h]), q1 = bc2(qv1[h]);
                A0 = q0 * k01 + A0; B0 = q0 * k23 + B0;
                A1 = q1 * k01 + A1; B1 = q1 * k23 + B1;
            }
            A0 = A0 * scl2; B0 = B0 * scl2;
            A1 = A1 * scl2; B1 = B1 * scl2;
            xa[2 * u] = A0; xa[2 * u + 1] = B0;
            xb[2 * u] = A1; xb[2 * u + 1] = B1;
            mva = max2(mva, max2(A0, B0)); sva = sva + A0 + B0;
            mvb = max2(mvb, max2(A1, B1)); svb = svb + A1 + B1;
        }
        const float m0 = grp_max16(fmaxf(mva.x, mva.y));
        const float m1 = grp_max16(fmaxf(mvb.x, mvb.y));
        const float tlo0 = m0 - 1.0f, thi0 = m0 - hispan;
        const float tlo1 = m1 - 1.0f, thi1 = m1 - hispan;

        float tau0, tau1;
        if (fast) {
            float sa0 = grp_sum16(sva.x + sva.y);
            float sa1 = grp_sum16(svb.x + svb.y);
            tau0 = fminf(fmaxf(sa0 * (1.0f / 512.0f), tlo0), thi0);
            tau1 = fminf(fmaxf(sa1 * (1.0f / 512.0f), tlo1), thi1);
#pragma unroll
            for (int itr = 0; itr < NSOLVE; ++itr) {
                f32x2 t20 = bc2(tau0), t21 = bc2(tau1);
                f32x2 s1A0 = zero2, s2A0 = zero2, cA0 = zero2;
                f32x2 s1A1 = zero2, s2A1 = zero2, cA1 = zero2;
#pragma unroll
                for (int j = 0; j < 16; ++j) {
                    f32x2 rp0 = max2(xa[j] - t20, zero2);
                    f32x2 rp1 = max2(xb[j] - t21, zero2);
                    s1A0 = s1A0 + rp0;
                    s1A1 = s1A1 + rp1;
                    s2A0 = rp0 * rp0 + s2A0;
                    s2A1 = rp1 * rp1 + s2A1;
                    cA0 = cA0 + min2(rp0 * big2, one2);
                    cA1 = cA1 + min2(rp1 * big2, one2);
                }
                float s10 = grp_sum16(s1A0.x + s1A0.y);
                float s20 = grp_sum16(s2A0.x + s2A0.y);
                float n0  = grp_sum16(cA0.x + cA0.y);
                float s11 = grp_sum16(s1A1.x + s1A1.y);
                float s21 = grp_sum16(s2A1.x + s2A1.y);
                float n1  = grp_sum16(cA1.x + cA1.y);
                float d0 = fmaxf(fmaf(s10, s10, -n0 * (s20 - 1.0f)), 0.0f);
                float d1 = fmaxf(fmaf(s11, s11, -n1 * (s21 - 1.0f)), 0.0f);
                tau0 += (s10 - sqrtf(d0)) / fmaxf(n0, 1.0f);
                tau1 += (s11 - sqrtf(d1)) / fmaxf(n1, 1.0f);
                tau0 = fminf(fmaxf(tau0, tlo0), thi0);
                tau1 = fminf(fmaxf(tau1, tlo1), thi1);
            }
        } else {
            // generic alpha: bisect + Newton (powf path), both rows
            tau0 = tlo0; tau1 = tlo1;
            float dm = 1.0f - hispan;
#pragma unroll
            for (int bi = 0; bi < NBISECT; ++bi) {
                dm *= 0.5f;
                float tm0 = tau0 + dm, tm1 = tau1 + dm;
                float f0 = 0.0f, f1 = 0.0f;
#pragma unroll
                for (int j = 0; j < 16; ++j) {
                    f0 += __powf(fmaxf(xa[j].x - tm0, 0.0f), expo);
                    f0 += __powf(fmaxf(xa[j].y - tm0, 0.0f), expo);
                    f1 += __powf(fmaxf(xb[j].x - tm1, 0.0f), expo);
                    f1 += __powf(fmaxf(xb[j].y - tm1, 0.0f), expo);
                }
                f0 = grp_sum16(f0);
                f1 = grp_sum16(f1);
                if (f0 >= 1.0f) tau0 = tm0;
                if (f1 >= 1.0f) tau1 = tm1;
            }
#pragma unroll
            for (int ni = 0; ni < NNEWTON; ++ni) {
                float f0 = 0, g0 = 0, f1 = 0, g1 = 0;
#pragma unroll
                for (int j = 0; j < 16; ++j) {
                    float r0x = fmaxf(xa[j].x - tau0, 0.0f);
                    float p0x = __powf(r0x, expo - 1.0f);
                    g0 += p0x; f0 += p0x * r0x;
                    float r0y = fmaxf(xa[j].y - tau0, 0.0f);
                    float p0y = __powf(r0y, expo - 1.0f);
                    g0 += p0y; f0 += p0y * r0y;
                    float r1x = fmaxf(xb[j].x - tau1, 0.0f);
                    float p1x = __powf(r1x, expo - 1.0f);
                    g1 += p1x; f1 += p1x * r1x;
                    float r1y = fmaxf(xb[j].y - tau1, 0.0f);
                    float p1y = __powf(r1y, expo - 1.0f);
                    g1 += p1y; f1 += p1y * r1y;
                }
                f0 = grp_sum16(f0); g0 = grp_sum16(g0);
                f1 = grp_sum16(f1); g1 = grp_sum16(g1);
                tau0 += (f0 - 1.0f) / fmaxf(expo * g0, 1e-30f);
                tau1 += (f1 - 1.0f) / fmaxf(expo * g1, 1e-30f);
                tau0 = fminf(fmaxf(tau0, tlo0), thi0);
                tau1 = fminf(fmaxf(tau1, tlo1), thi1);
            }
        }

        // ---- final p (unnormalized) back into xa/xb; S packed
        float S0, S1;
        if (fast) {
            f32x2 t20 = bc2(tau0), t21 = bc2(tau1);
            f32x2 SA0 = zero2, SA1 = zero2;
#pragma unroll
            for (int j = 0; j < 16; ++j) {
                f32x2 r0 = max2(xa[j] - t20, zero2);
                f32x2 r1 = max2(xb[j] - t21, zero2);
                f32x2 p0 = r0 * r0, p1 = r1 * r1;
                xa[j] = p0; xb[j] = p1;
                SA0 = SA0 + p0; SA1 = SA1 + p1;
            }
            S0 = SA0.x + SA0.y;
            S1 = SA1.x + SA1.y;
        } else {
            float s0 = 0.0f, s1 = 0.0f;
#pragma unroll
            for (int j = 0; j < 16; ++j) {
                float p0x = __powf(fmaxf(xa[j].x - tau0, 0.0f), expo);
                float p0y = __powf(fmaxf(xa[j].y - tau0, 0.0f), expo);
                float p1x = __powf(fmaxf(xb[j].x - tau1, 0.0f), expo);
                float p1y = __powf(fmaxf(xb[j].y - tau1, 0.0f), expo);
                xa[j] = mk2(p0x, p0y); xb[j] = mk2(p1x, p1y);
                s0 += p0x + p0y; s1 += p1x + p1y;
            }
            S0 = s0; S1 = s1;
        }
        S0 = grp_sum16(S0);
        S1 = grp_sum16(S1);
        const float iS0 = 1.0f / S0, iS1 = 1.0f / S1;

        // ---- res[h,i] = invS * sum_j p[j] v[h,j]; V reads shared by 2 rows
#pragma unroll
        for (int h = 0; h < 8; ++h) {
            f32x2 aA0 = zero2, aB0 = zero2, aA1 = zero2, aB1 = zero2;
#pragma unroll 2
            for (int u = 0; u < 8; ++u) {
                float4 v4 = *(const float4*)&vs[h * 512 + lx * 4 + 64 * u];
                f32x2 v01 = mk2(v4.x, v4.y), v23 = mk2(v4.z, v4.w);
                aA0 = xa[2 * u] * v01 + aA0;
                aB0 = xa[2 * u + 1] * v23 + aB0;
                aA1 = xb[2 * u] * v01 + aA1;
                aB1 = xb[2 * u + 1] * v23 + aB1;
            }
            float a0 = (aA0.x + aA0.y) + (aB0.x + aB0.y);
            float a1 = (aA1.x + aA1.y) + (aB1.x + aB1.y);
            a0 = grp_sum16(a0) * iS0;
            a1 = grp_sum16(a1) * iS1;
            if (lx == h) {
                resg[(size_t)t * 4096 + h * 512 + base + il0] = a0;
                resg[(size_t)t * 4096 + h * 512 + base + il1] = a1;
            }
        }
    }
}

// ---------------------------------------------------------------------------
__global__ __launch_bounds__(256) void reduce_bias(
    const float* __restrict__ part, const float* __restrict__ bu,
    float* __restrict__ out, int MN, int S)
{
    int i = blockIdx.x * 256 + threadIdx.x;
    if (i >= MN) return;
    float a = bu[i & 511];
#pragma unroll
    for (int s = 0; s < 8; ++s) a += part[(size_t)s * MN + i];
    out[i] = a;
}

// ---------------------------------------------------------------------------
extern "C" void kernel_launch(void* const* d_in, const int* in_sizes, int n_in,
                              void* d_out, int out_size, void* d_ws, size_t ws_size,
                              hipStream_t stream)
{
    const float* x  = (const float*)d_in[0];
    const float* Wq = (const float*)d_in[1];
    const float* bq = (const float*)d_in[2];
    const float* Wk = (const float*)d_in[3];
    const float* bk = (const float*)d_in[4];
    const float* Wv = (const float*)d_in[5];
    const float* bv = (const float*)d_in[6];
    const float* Wu = (const float*)d_in[7];
    const float* bu = (const float*)d_in[8];
    const float* al = (const float*)d_in[9];
    float* out = (float*)d_out;
    float* ws = (float*)d_ws;

    // ws layout (floats): q[2M] | k[2M] | v[2M]
    // res aliases q (disjoint per-block row slices); split-K partials alias k.
    float* q = ws;
    float* k = ws + 2097152;
    float* v = ws + 2 * 2097152;
    float* res = q;
    float* part = k;

    dim3 blk(256);

    dim3 g1(4096 / TN, 512 / TM, 1);
    gemm_tiled<<<g1, blk, 0, stream>>>(x, 512, Wq, 4096, q, 4096, 512, 4096, 512, bq);
    gemm_tiled<<<g1, blk, 0, stream>>>(x, 512, Wk, 4096, k, 4096, 512, 4096, 512, bk);
    gemm_tiled<<<g1, blk, 0, stream>>>(x, 512, Wv, 4096, v, 4096, 512, 4096, 512, bv);

    // fused scores + alpha-entmax + P*V^T, half token per block
    attn_entmax<<<dim3(1024), blk, 0, stream>>>(q, k, v, res, al);

    dim3 g3(512 / TN, 512 / TM, 8);
    gemm_tiled<<<g3, blk, 0, stream>>>(res, 4096, Wu, 512, part, 512, 512, 512, 512, nullptr);
    reduce_bias<<<dim3(262144 / 256), blk, 0, stream>>>(part, bu, out, 262144, 8);
}